// Round 9
// baseline (707.781 us; speedup 1.0000x reference)
//
#include <hip/hip_runtime.h>
#include <cstdint>
#include <cstddef>

// RobustGCN forward on MI355X.
//   1. graph prep — bucket sort (bucket = src>>7), pairs PACKED to u32.
//      Merged launches: hist+prep_w, boff+bscan(local rescan), scan3+scan2.
//      hist -> btotal -> boff2 -> bscatter(u32) -> countN(+dd) -> scan1 ->
//      scan3m -> partC.  (r6: global-atomic scatter = 15x write-amp. Bucket wins.)
//   2. GEMM1 v8 (gemm1d): BM=BN=128, BK=32, 4 waves (2x2), acc[4][4].
//      LDS-pipe-bound analysis (r8): 72KB LDS traffic/block-iter vs ~727cy slot.
//      Fix: B OUT of LDS — W1t is 512KB L2-resident; bf[4] loaded directly
//      global->reg each iter (wave covers 16 rows x 64B segments). LDS traffic
//      72->48KB/iter, DMA 24->16KB/iter. A stays gload_lds f32 + ^row&7 swizzle,
//      cvt at frag build, dbuf, 1 barrier/iter, 3 blocks/CU.
//      (r8: BM=64 raised occupancy 28->41% but WORSE bytes/FLOP -> 193us.
//       Occupancy is not the binding constraint; LDS/staging traffic is.)
//   3. GEMM2 v2: gload16-staged (0-conflict f16 layout), acc[2][8];
//      epilogue folds deg weights: Mcat[r][c]=pack_h2(dis_r*m*a, di_r*v*a^2).
//   4. fused dual SpMM (CSR, wave/node, lane/class, 8 gathers in flight)
//      + sample*sqrt(var) + log_softmax.

typedef _Float16 h8 __attribute__((ext_vector_type(8)));
typedef _Float16 h2 __attribute__((ext_vector_type(2)));
typedef float f32x4 __attribute__((ext_vector_type(4)));
typedef unsigned int uint32;

#define BSHIFT 7              // 128 nodes per bucket
#define NCHUNK 256            // edge chunks (blocks) in sort passes

static __device__ __forceinline__ float elu_f(float z) {
  return z > 0.f ? z : expm1f(z);
}

// async global->LDS, 16B per lane. Dest must be wave-linear (base + lane*16).
static __device__ __forceinline__ void gload16(const void* g, void* l) {
  __builtin_amdgcn_global_load_lds(
      (__attribute__((address_space(1))) void*)g,
      (__attribute__((address_space(3))) void*)l, 16, 0, 0);
}

static __device__ __forceinline__ h8 cvt8(float4 a, float4 b) {
  return h8{(_Float16)a.x, (_Float16)a.y, (_Float16)a.z, (_Float16)a.w,
            (_Float16)b.x, (_Float16)b.y, (_Float16)b.z, (_Float16)b.w};
}

// ---------------- merged hist + weight prep ----------------
// blocks [0, NCHUNK): edge histogram per chunk; blocks [NCHUNK, ...): W transpose.
__global__ __launch_bounds__(256) void histprep_k(
    const int* __restrict__ esrc, int E, int chunk, int* __restrict__ h, int NB,
    const float* __restrict__ Wm0, const float* __restrict__ Wv0,
    const float* __restrict__ Wm1, const float* __restrict__ Wv1,
    _Float16* __restrict__ W1t, _Float16* __restrict__ W2t) {
  int t = threadIdx.x;
  if (blockIdx.x < NCHUNK) {
    __shared__ int sh[1024];
    for (int i = t; i < NB; i += 256) sh[i] = 0;
    __syncthreads();
    int e0 = blockIdx.x * chunk;
    int e1 = min(e0 + chunk, E);
    for (int e = e0 + t; e < e1; e += 256) atomicAdd(&sh[esrc[e] >> BSHIFT], 1);
    __syncthreads();
    for (int i = t; i < NB; i += 256) h[blockIdx.x * NB + i] = sh[i];
  } else {
    int idx = (blockIdx.x - NCHUNK) * 256 + t;
    if (idx < 512 * 512) {
      int n = idx >> 9, k = idx & 511;
      float v = (n < 256) ? Wm0[k * 256 + n] : Wv0[k * 256 + (n - 256)];
      W1t[idx] = (_Float16)v;
    }
    if (idx < 128 * 512) {
      int n = idx >> 9, k = idx & 511;
      float v = 0.f;
      if (n < 64) { if (k < 256) v = Wm1[k * 64 + n]; }
      else        { if (k >= 256) v = Wv1[(k - 256) * 64 + (n - 64)]; }
      W2t[idx] = (_Float16)v;
    }
  }
}

__global__ __launch_bounds__(256) void btotal_k(const int* __restrict__ h,
                                                int* __restrict__ tot, int NB) {
  int b = blockIdx.x, t = threadIdx.x;
  int v = h[t * NB + b];
#pragma unroll
  for (int off = 32; off; off >>= 1) v += __shfl_xor(v, off, 64);
  __shared__ int sw[4];
  if ((t & 63) == 0) sw[t >> 6] = v;
  __syncthreads();
  if (t == 0) tot[b] = sw[0] + sw[1] + sw[2] + sw[3];
}

// boff2: each block locally scans tot[] (NB <= 1024) -> bucket base, then scans
// its bucket's per-chunk counts. Block 0 also publishes base[] for countN/partC.
__global__ __launch_bounds__(1024) void boff2_k(const int* __restrict__ tot,
                                                int* __restrict__ h,
                                                int* __restrict__ base, int NB) {
  __shared__ int sh[1024];
  __shared__ int bbs;
  int b = blockIdx.x, t = threadIdx.x;
  int v = (t < NB) ? tot[t] : 0;
  sh[t] = v;
  __syncthreads();
  for (int off = 1; off < 1024; off <<= 1) {
    int add = (t >= off) ? sh[t - off] : 0;
    __syncthreads();
    sh[t] += add;
    __syncthreads();
  }
  if (b == 0) {
    if (t < NB) base[t] = sh[t] - v;
    if (t == 0) base[NB] = sh[NB - 1];
  }
  if (t == 0) bbs = (b > 0) ? sh[b - 1] : 0;
  __syncthreads();
  // per-chunk scan for bucket b (256 chunks)
  int hv = (t < 256) ? h[t * NB + b] : 0;
  __syncthreads();          // sh reuse safe: all reads above done
  if (t < 256) sh[t] = hv;
  __syncthreads();
  for (int off = 1; off < 256; off <<= 1) {
    int add = (t >= off && t < 256) ? sh[t - off] : 0;
    __syncthreads();
    if (t < 256) sh[t] += add;
    __syncthreads();
  }
  if (t < 256) h[t * NB + b] = bbs + sh[t] - hv;
}

// packed pairs: (src&127)<<25 | dst   (dst < 2^25)
__global__ __launch_bounds__(256) void bscatter_k(
    const int* __restrict__ esrc, const int* __restrict__ edst, int E, int chunk,
    const int* __restrict__ h, uint32* __restrict__ pairs, int NB) {
  __shared__ int lcur[1024];
  int t = threadIdx.x;
  for (int i = t; i < NB; i += 256) lcur[i] = h[blockIdx.x * NB + i];
  __syncthreads();
  int e0 = blockIdx.x * chunk;
  int e1 = min(e0 + chunk, E);
  for (int e = e0 + t; e < e1; e += 256) {
    int s = esrc[e], d = edst[e];
    int pos = atomicAdd(&lcur[s >> BSHIFT], 1);
    pairs[pos] = ((uint32)(s & 127) << 25) | (uint32)d;
  }
}

// per-node degree + degree weights
__global__ __launch_bounds__(256) void countN_k(
    const uint32* __restrict__ pairs, const int* __restrict__ base,
    int* __restrict__ cnt, float2* __restrict__ dd, int n) {
  __shared__ int c128[128];
  int b = blockIdx.x, t = threadIdx.x;
  if (t < 128) c128[t] = 0;
  __syncthreads();
  int lo = base[b], hi = base[b + 1];
  for (int i = lo + t; i < hi; i += 256) atomicAdd(&c128[pairs[i] >> 25], 1);
  __syncthreads();
  if (t < 128) {
    int node = b * 128 + t;
    if (node < n) {
      int c = c128[t];
      cnt[node] = c;
      float d = (float)(c + 1);  // +1 self loop
      dd[node] = make_float2(rsqrtf(d), 1.f / d);
    }
  }
}

__global__ __launch_bounds__(256) void partC_k(
    const uint32* __restrict__ pairs, const int* __restrict__ base,
    const int* __restrict__ rs, int* __restrict__ csr, int n) {
  __shared__ int lcur[128];
  int b = blockIdx.x, t = threadIdx.x;
  if (t < 128) {
    int node = b * 128 + t;
    lcur[t] = (node < n) ? rs[node] : 0;
  }
  __syncthreads();
  int lo = base[b], hi = base[b + 1];
  for (int i = lo + t; i < hi; i += 256) {
    uint32 p = pairs[i];
    int pos = atomicAdd(&lcur[p >> 25], 1);
    csr[pos] = (int)(p & 0x1FFFFFFu);
  }
}

// ---------------- padded row-start scan ----------------
__global__ void scan1_k(const int* __restrict__ cnt, int* __restrict__ excl,
                        int* __restrict__ bsum, int n) {
  __shared__ int sh[256];
  int t = threadIdx.x, idx = blockIdx.x * 256 + t;
  int v = (idx < n) ? ((cnt[idx] + 3) & ~3) : 0;
  sh[t] = v;
  __syncthreads();
  for (int off = 1; off < 256; off <<= 1) {
    int add = (t >= off) ? sh[t - off] : 0;
    __syncthreads();
    sh[t] += add;
    __syncthreads();
  }
  if (idx < n) excl[idx] = sh[t] - v;
  if (t == 255) bsum[blockIdx.x] = sh[255];
}

// scan3m: local scan of bsum (nb <= 512) + add. 512 elems/block.
__global__ __launch_bounds__(512) void scan3m_k(int* __restrict__ excl,
                                                const int* __restrict__ bsum,
                                                int nb, int n) {
  __shared__ int sh[512];
  int t = threadIdx.x;
  int v = (t < nb) ? bsum[t] : 0;
  sh[t] = v;
  __syncthreads();
  for (int off = 1; off < 512; off <<= 1) {
    int add = (t >= off) ? sh[t - off] : 0;
    __syncthreads();
    sh[t] += add;
    __syncthreads();
  }
  int idx = blockIdx.x * 512 + t;
  if (idx < n) {
    int k = idx >> 8;                     // bsum block of this element
    excl[idx] += (k > 0) ? sh[k - 1] : 0;
  }
}

// ---------------- GEMM1 v8 (gemm1d): Hcat = act(x @ W1t^T + b) ----------------
// BM=BN=128, BK=32, 4 waves (2m x 2n), acc[4][4]. A: gload_lds f32 dbuf 32KB
// (^row&7 slot swizzle), cvt at frag build. B: DIRECT global->reg from L2-hot
// W1t (no LDS). 1 barrier/iter guards A only. 3 blocks/CU.
__global__ __launch_bounds__(256) void gemm1d_k(
    const float* __restrict__ A, const _Float16* __restrict__ Bt,
    const float* __restrict__ b0, const float* __restrict__ b1,
    _Float16* __restrict__ out, int M, int mtiles) {
  __shared__ __align__(16) unsigned char ldsb[36864];  // A dbuf 32KB; epilogue 34.8KB

  const int sg = blockIdx.x >> 5, loc = blockIdx.x & 31;
  const int nt = loc >> 3, mtl = loc & 7;
  const int mt = sg * 8 + mtl;
  if (mt >= mtiles) return;
  const int m0 = mt * 128, n0 = nt * 128;
  const int t = threadIdx.x;
  const int lane = t & 63;
  const int wave = t >> 6;
  const int wm = wave >> 1, wn = wave & 1;
  const int lr = lane & 15, quad = lane >> 4;

  const int ra = t >> 3;
  const int asw = ((t & 7) ^ (ra & 7)) << 2;

  // B direct: lane reads rows n0+wn*64+j*16+lr, cols [kt+quad*8, +8)
  const _Float16* bbase = Bt + (size_t)(n0 + wn * 64 + lr) * 512 + quad * 8;

  f32x4 acc[4][4] = {};

  auto stageA = [&](int b, int kt) {
#pragma unroll
    for (int i = 0; i < 4; i++) {
      const float* src = A + (size_t)min(m0 + i * 32 + ra, M - 1) * 512 + kt + asw;
      gload16(src, ldsb + b * 16384 + i * 4096 + t * 16);
    }
  };

  stageA(0, 0);
  __syncthreads();

  int cur = 0;
  const int zA = lr & 7;
  for (int kt = 0; kt < 512; kt += 32) {
    // B frags for this iter: direct from L2 (issued first, consumed last)
    h8 bf[4];
#pragma unroll
    for (int j = 0; j < 4; j++)
      bf[j] = *(const h8*)(bbase + (size_t)j * 16 * 512 + kt);
    if (kt + 32 < 512) stageA(cur ^ 1, kt + 32);
    const unsigned char* Ab = ldsb + cur * 16384;
    h8 af[4];
#pragma unroll
    for (int i = 0; i < 4; i++) {
      int R = wm * 64 + i * 16 + lr;
      const float4 a0 = *(const float4*)(Ab + R * 128 + (((2 * quad) ^ zA) << 4));
      const float4 a1 = *(const float4*)(Ab + R * 128 + (((2 * quad + 1) ^ zA) << 4));
      af[i] = cvt8(a0, a1);
    }
#pragma unroll
    for (int i = 0; i < 4; i++)
#pragma unroll
      for (int j = 0; j < 4; j++)
        acc[i][j] = __builtin_amdgcn_mfma_f32_16x16x32_f16(af[i], bf[j], acc[i][j], 0, 0, 0);
    __syncthreads();
    cur ^= 1;
  }

  // epilogue: bias+act in regs -> f16 LDS tile (stride 136) -> 16B coalesced stores
  _Float16* lt = (_Float16*)ldsb;
#pragma unroll
  for (int j = 0; j < 4; j++) {
    int gc = n0 + wn * 64 + j * 16 + lr;
    float bj = (gc < 256) ? b0[gc] : b1[gc - 256];
#pragma unroll
    for (int i = 0; i < 4; i++) {
#pragma unroll
      for (int r = 0; r < 4; r++) {
        float z = acc[i][j][r] + bj;
        float v = (gc < 256) ? elu_f(z) : fmaxf(z, 0.f);
        lt[(wm * 64 + i * 16 + quad * 4 + r) * 136 + wn * 64 + j * 16 + lr] = (_Float16)v;
      }
    }
  }
  __syncthreads();
  {
    const int row = t >> 1, col0 = (t & 1) * 64;
    const int gr = m0 + row;
    if (gr < M) {
      _Float16* dst = out + (size_t)gr * 512 + n0 + col0;
#pragma unroll
      for (int k = 0; k < 8; k++)
        *(h8*)(dst + k * 8) = *(h8*)&lt[row * 136 + col0 + k * 8];
    }
  }
}

// ---------------- GEMM2 v2 + fused attention (gload16-staged) ----------------
__global__ __launch_bounds__(256) void gemm2_k(
    const _Float16* __restrict__ A, const _Float16* __restrict__ Bt,
    const float* __restrict__ bm1, const float* __restrict__ bv1,
    const float2* __restrict__ dd, uint32* __restrict__ Mcat, int M) {
  __shared__ __align__(16) unsigned char ldsb[32768];
  const int m0 = blockIdx.x * 128;
  const int t = threadIdx.x;
  const int lane = t & 63;
  const int wave = t >> 6;
  const int lr = lane & 15, quad = lane >> 4;

  const int rb = t >> 2;
  const int sw = ((t & 3) ^ ((t >> 3) & 3)) << 3;     // inv-swizzled f16 col

  f32x4 acc[2][8] = {};

  auto stage = [&](int b, int kt) {
#pragma unroll
    for (int i = 0; i < 2; i++) {                     // A: 128 rows x 32 f16
      const _Float16* src = A + (size_t)min(m0 + i * 64 + rb, M - 1) * 512 + kt + sw;
      gload16(src, ldsb + b * 16384 + i * 4096 + t * 16);
    }
#pragma unroll
    for (int i = 0; i < 2; i++) {                     // B: 128 rows x 32 f16
      const _Float16* src = Bt + (size_t)(i * 64 + rb) * 512 + kt + sw;
      gload16(src, ldsb + b * 16384 + 8192 + i * 4096 + t * 16);
    }
  };

  stage(0, 0);
  __syncthreads();

  const int z = (lr >> 1) & 3;
  int cur = 0;
  for (int kt = 0; kt < 512; kt += 32) {
    if (kt + 32 < 512) stage(cur ^ 1, kt + 32);
    const unsigned char* Ab = ldsb + cur * 16384;
    const unsigned char* Bb = Ab + 8192;
    h8 af[2], bf[8];
#pragma unroll
    for (int i = 0; i < 2; i++) {
      int row = wave * 32 + i * 16 + lr;
      af[i] = *(const h8*)(Ab + row * 64 + ((quad ^ z) << 4));
    }
#pragma unroll
    for (int j = 0; j < 8; j++) {
      int row = j * 16 + lr;
      bf[j] = *(const h8*)(Bb + row * 64 + ((quad ^ z) << 4));
    }
#pragma unroll
    for (int i = 0; i < 2; i++)
#pragma unroll
      for (int j = 0; j < 8; j++)
        acc[i][j] = __builtin_amdgcn_mfma_f32_16x16x32_f16(af[i], bf[j], acc[i][j], 0, 0, 0);
    __syncthreads();
    cur ^= 1;
  }

  float2 wrow[2][4];
#pragma unroll
  for (int i = 0; i < 2; i++)
#pragma unroll
    for (int r = 0; r < 4; r++) {
      int gr = m0 + wave * 32 + i * 16 + quad * 4 + r;
      wrow[i][r] = (gr < M) ? dd[gr] : make_float2(0.f, 0.f);
    }

#pragma unroll
  for (int jm = 0; jm < 4; jm++) {
    int c = jm * 16 + lr;                 // class col 0..63
    float bm = bm1[c], bv = bv1[c];
#pragma unroll
    for (int i = 0; i < 2; i++) {
#pragma unroll
      for (int r = 0; r < 4; r++) {
        int gr = m0 + wave * 32 + i * 16 + quad * 4 + r;
        if (gr < M) {
          float zm = acc[i][jm][r] + bm;
          float zv = acc[i][4 + jm][r] + bv;
          float m = elu_f(zm);
          float v = fmaxf(zv, 0.f) + 1e-6f;
          float a = __expf(-v);
          h2 pk;
          pk.x = (_Float16)(m * a * wrow[i][r].x);       // dis_r * mean*attn
          pk.y = (_Float16)(v * a * a * wrow[i][r].y);   // di_r * var*attn^2
          Mcat[(size_t)gr * 64 + c] = __builtin_bit_cast(uint32, pk);
        }
      }
    }
  }
}

// ---------------- fused dual SpMM + reparam + log_softmax ----------------
__global__ __launch_bounds__(256) void spmm_final_k(
    const uint32* __restrict__ Mcat, const float2* __restrict__ dd,
    const int* __restrict__ row_start, const int* __restrict__ cnt,
    const int* __restrict__ csr, const float* __restrict__ sample,
    float* __restrict__ out, int n) {
  int wid = threadIdx.x >> 6, lane = threadIdx.x & 63;
  int r = blockIdx.x * 4 + wid;
  if (r >= n) return;
  float2 wr = dd[r];
  h2 self = __builtin_bit_cast(h2, Mcat[(size_t)r * 64 + lane]);
  float Sm = (float)self.x;           // already dis_r-scaled
  float Sv = (float)self.y;           // already di_r-scaled
  int start = __builtin_amdgcn_readfirstlane(row_start[r]);
  int c = __builtin_amdgcn_readfirstlane(cnt[r]);
  int j = 0;
  for (; j + 8 <= c; j += 8) {
    int4 da = *(const int4*)(csr + start + j);
    int4 db = *(const int4*)(csr + start + j + 4);
    h2 p0 = __builtin_bit_cast(h2, Mcat[(size_t)da.x * 64 + lane]);
    h2 p1 = __builtin_bit_cast(h2, Mcat[(size_t)da.y * 64 + lane]);
    h2 p2 = __builtin_bit_cast(h2, Mcat[(size_t)da.z * 64 + lane]);
    h2 p3 = __builtin_bit_cast(h2, Mcat[(size_t)da.w * 64 + lane]);
    h2 p4 = __builtin_bit_cast(h2, Mcat[(size_t)db.x * 64 + lane]);
    h2 p5 = __builtin_bit_cast(h2, Mcat[(size_t)db.y * 64 + lane]);
    h2 p6 = __builtin_bit_cast(h2, Mcat[(size_t)db.z * 64 + lane]);
    h2 p7 = __builtin_bit_cast(h2, Mcat[(size_t)db.w * 64 + lane]);
    Sm += (float)p0.x + (float)p1.x + (float)p2.x + (float)p3.x;
    Sv += (float)p0.y + (float)p1.y + (float)p2.y + (float)p3.y;
    Sm += (float)p4.x + (float)p5.x + (float)p6.x + (float)p7.x;
    Sv += (float)p4.y + (float)p5.y + (float)p6.y + (float)p7.y;
  }
  if (j + 4 <= c) {
    int4 d4 = *(const int4*)(csr + start + j);
    h2 p0 = __builtin_bit_cast(h2, Mcat[(size_t)d4.x * 64 + lane]);
    h2 p1 = __builtin_bit_cast(h2, Mcat[(size_t)d4.y * 64 + lane]);
    h2 p2 = __builtin_bit_cast(h2, Mcat[(size_t)d4.z * 64 + lane]);
    h2 p3 = __builtin_bit_cast(h2, Mcat[(size_t)d4.w * 64 + lane]);
    Sm += (float)p0.x + (float)p1.x + (float)p2.x + (float)p3.x;
    Sv += (float)p0.y + (float)p1.y + (float)p2.y + (float)p3.y;
    j += 4;
  }
  for (; j < c; j++) {
    int d = csr[start + j];
    h2 p = __builtin_bit_cast(h2, Mcat[(size_t)d * 64 + lane]);
    Sm += (float)p.x;
    Sv += (float)p.y;
  }
  float mean = wr.x * Sm;
  float var = wr.y * Sv;
  float o = mean + sample[(size_t)r * 64 + lane] * sqrtf(var);
  float mx = o;
#pragma unroll
  for (int off = 32; off; off >>= 1) mx = fmaxf(mx, __shfl_xor(mx, off, 64));
  float ex = __expf(o - mx);
  float s = ex;
#pragma unroll
  for (int off = 32; off; off >>= 1) s += __shfl_xor(s, off, 64);
  out[(size_t)r * 64 + lane] = o - mx - logf(s);
}

// ---------------- launch ----------------
extern "C" void kernel_launch(void* const* d_in, const int* in_sizes, int n_in,
                              void* d_out, int out_size, void* d_ws, size_t ws_size,
                              hipStream_t stream) {
  (void)n_in; (void)out_size; (void)ws_size;
  const float* x    = (const float*)d_in[0];
  const float* Wm0  = (const float*)d_in[1];
  const float* bm0  = (const float*)d_in[2];
  const float* Wv0  = (const float*)d_in[3];
  const float* bv0  = (const float*)d_in[4];
  const float* Wm1  = (const float*)d_in[5];
  const float* bm1  = (const float*)d_in[6];
  const float* Wv1  = (const float*)d_in[7];
  const float* bv1  = (const float*)d_in[8];
  const float* sample = (const float*)d_in[9];
  const int* esrc   = (const int*)d_in[10];
  const int* edst   = (const int*)d_in[11];
  float* out = (float*)d_out;

  const int N = in_sizes[0] / 512;
  const int E = in_sizes[10];
  const int NB = (N + 127) >> BSHIFT;          // 128-node buckets
  const int chunk = (E + NCHUNK - 1) / NCHUNK;

  uint8_t* p = (uint8_t*)d_ws;
  size_t off = 0;
  auto alloc = [&](size_t bytes) -> void* {
    void* r = p + off;
    off += (bytes + 255) & ~(size_t)255;
    return r;
  };
  _Float16* W1t  = (_Float16*)alloc((size_t)512 * 512 * 2);
  _Float16* W2t  = (_Float16*)alloc((size_t)128 * 512 * 2);
  _Float16* Hcat = (_Float16*)alloc((size_t)N * 512 * 2);
  uint32*   Mcat = (uint32*)alloc((size_t)N * 64 * 4);
  int*   cnt    = (int*)alloc((size_t)N * 4);
  float2* dd    = (float2*)alloc((size_t)N * 8);
  int*   rs     = (int*)alloc((size_t)N * 4);
  int*   h      = (int*)alloc((size_t)NCHUNK * NB * 4);
  int*   tot    = (int*)alloc((size_t)(NB + 1) * 4);
  int*   base   = (int*)alloc((size_t)(NB + 1) * 4);
  int*   bsum   = (int*)alloc(2048);
  int*   csr    = (int*)alloc((size_t)(E + 4 * N) * 4);  // padded rows
  // bucket-sorted packed pairs only live before gemm1 writes Hcat:
  uint32* pairs = (uint32*)Hcat;   // E*4 = 12.8MB <= Hcat's 102.4MB

  const int nbN = (N + 255) / 256;

  histprep_k<<<NCHUNK + 1024, 256, 0, stream>>>(esrc, E, chunk, h, NB,
                                                Wm0, Wv0, Wm1, Wv1, W1t, W2t);
  btotal_k<<<NB, 256, 0, stream>>>(h, tot, NB);
  boff2_k<<<NB, 1024, 0, stream>>>(tot, h, base, NB);
  bscatter_k<<<NCHUNK, 256, 0, stream>>>(esrc, edst, E, chunk, h, pairs, NB);
  countN_k<<<NB, 256, 0, stream>>>(pairs, base, cnt, dd, N);
  scan1_k<<<nbN, 256, 0, stream>>>(cnt, rs, bsum, N);
  scan3m_k<<<(N + 511) / 512, 512, 0, stream>>>(rs, bsum, nbN, N);
  partC_k<<<NB, 256, 0, stream>>>(pairs, base, rs, csr, N);

  const int mtiles = (N + 127) / 128;
  const int sgroups = (mtiles + 7) / 8;
  gemm1d_k<<<sgroups * 32, 256, 0, stream>>>(x, W1t, bm0, bv0, Hcat, N, mtiles);
  gemm2_k<<<mtiles, 256, 0, stream>>>(Hcat, W2t, bm1, bv1, dd, Mcat, N);
  spmm_final_k<<<(N + 3) / 4, 256, 0, stream>>>(Mcat, dd, rs, cnt, csr, sample, out, N);
}

// Round 10
// 687.431 us; speedup vs baseline: 1.0296x; 1.0296x over previous
//
#include <hip/hip_runtime.h>
#include <cstdint>
#include <cstddef>

// RobustGCN forward on MI355X.
//   1. graph prep — bucket sort (bucket = src>>7), pairs PACKED to u32.
//      Merged launches: hist+prep_w, boff+bscan(local rescan), scan3+scan2.
//      (r6: global-atomic scatter = 15x write-amp. Bucket-dense wins.)
//   2. GEMM1 (gemm1f, r2/r7-proven 178us local optimum): BM=BN=128, BK=32,
//      4 waves, dbuf 48KB LDS, A f32 + B f16 via global_load_lds w16 (linear
//      dest, inv-swizzled src), cvt at frag build, 3 blocks/CU.
//      Variant ledger: h 151(+77 cvtx) / BM64 193 / B-direct 201 / reg-staged
//      226 / 3buf 204 / BN512 253. r9 falsified LDS-pipe theory: conflicts
//      unchanged with B out of LDS -> B LDS path was free; don't touch.
//   3. GEMM2 (gload16-staged, 0-conflict f16 layout), acc[2][8]; epilogue
//      folds deg weights: Mcat[r][c] = pack_h2(dis_r*m*e^-v, di_r*v*e^-2v).
//   4. spmm v2 DUAL-ROW: lanes 0-31 -> row 2i, lanes 32-63 -> row 2i+1;
//      lane loads uint2 (2 classes, 8B) -> half the VMEM instrs/edge, 2 rows
//      per wave, same gathered bytes. Sub-group shfl (width 32) softmax.

typedef _Float16 h8 __attribute__((ext_vector_type(8)));
typedef _Float16 h2 __attribute__((ext_vector_type(2)));
typedef float f32x4 __attribute__((ext_vector_type(4)));
typedef unsigned int uint32;

#define BSHIFT 7              // 128 nodes per bucket
#define NCHUNK 256            // edge chunks (blocks) in sort passes

static __device__ __forceinline__ float elu_f(float z) {
  return z > 0.f ? z : expm1f(z);
}

// async global->LDS, 16B per lane. Dest must be wave-linear (base + lane*16).
static __device__ __forceinline__ void gload16(const void* g, void* l) {
  __builtin_amdgcn_global_load_lds(
      (__attribute__((address_space(1))) void*)g,
      (__attribute__((address_space(3))) void*)l, 16, 0, 0);
}

static __device__ __forceinline__ h8 cvt8(float4 a, float4 b) {
  return h8{(_Float16)a.x, (_Float16)a.y, (_Float16)a.z, (_Float16)a.w,
            (_Float16)b.x, (_Float16)b.y, (_Float16)b.z, (_Float16)b.w};
}

// ---------------- merged hist + weight prep ----------------
__global__ __launch_bounds__(256) void histprep_k(
    const int* __restrict__ esrc, int E, int chunk, int* __restrict__ h, int NB,
    const float* __restrict__ Wm0, const float* __restrict__ Wv0,
    const float* __restrict__ Wm1, const float* __restrict__ Wv1,
    _Float16* __restrict__ W1t, _Float16* __restrict__ W2t) {
  int t = threadIdx.x;
  if (blockIdx.x < NCHUNK) {
    __shared__ int sh[1024];
    for (int i = t; i < NB; i += 256) sh[i] = 0;
    __syncthreads();
    int e0 = blockIdx.x * chunk;
    int e1 = min(e0 + chunk, E);
    for (int e = e0 + t; e < e1; e += 256) atomicAdd(&sh[esrc[e] >> BSHIFT], 1);
    __syncthreads();
    for (int i = t; i < NB; i += 256) h[blockIdx.x * NB + i] = sh[i];
  } else {
    int idx = (blockIdx.x - NCHUNK) * 256 + t;
    if (idx < 512 * 512) {
      int n = idx >> 9, k = idx & 511;
      float v = (n < 256) ? Wm0[k * 256 + n] : Wv0[k * 256 + (n - 256)];
      W1t[idx] = (_Float16)v;
    }
    if (idx < 128 * 512) {
      int n = idx >> 9, k = idx & 511;
      float v = 0.f;
      if (n < 64) { if (k < 256) v = Wm1[k * 64 + n]; }
      else        { if (k >= 256) v = Wv1[(k - 256) * 64 + (n - 64)]; }
      W2t[idx] = (_Float16)v;
    }
  }
}

__global__ __launch_bounds__(256) void btotal_k(const int* __restrict__ h,
                                                int* __restrict__ tot, int NB) {
  int b = blockIdx.x, t = threadIdx.x;
  int v = h[t * NB + b];
#pragma unroll
  for (int off = 32; off; off >>= 1) v += __shfl_xor(v, off, 64);
  __shared__ int sw[4];
  if ((t & 63) == 0) sw[t >> 6] = v;
  __syncthreads();
  if (t == 0) tot[b] = sw[0] + sw[1] + sw[2] + sw[3];
}

// boff2: each block locally scans tot[] -> bucket base, then scans its bucket's
// per-chunk counts. Block 0 also publishes base[].
__global__ __launch_bounds__(1024) void boff2_k(const int* __restrict__ tot,
                                                int* __restrict__ h,
                                                int* __restrict__ base, int NB) {
  __shared__ int sh[1024];
  __shared__ int bbs;
  int b = blockIdx.x, t = threadIdx.x;
  int v = (t < NB) ? tot[t] : 0;
  sh[t] = v;
  __syncthreads();
  for (int off = 1; off < 1024; off <<= 1) {
    int add = (t >= off) ? sh[t - off] : 0;
    __syncthreads();
    sh[t] += add;
    __syncthreads();
  }
  if (b == 0) {
    if (t < NB) base[t] = sh[t] - v;
    if (t == 0) base[NB] = sh[NB - 1];
  }
  if (t == 0) bbs = (b > 0) ? sh[b - 1] : 0;
  __syncthreads();
  int hv = (t < 256) ? h[t * NB + b] : 0;
  __syncthreads();
  if (t < 256) sh[t] = hv;
  __syncthreads();
  for (int off = 1; off < 256; off <<= 1) {
    int add = (t >= off && t < 256) ? sh[t - off] : 0;
    __syncthreads();
    if (t < 256) sh[t] += add;
    __syncthreads();
  }
  if (t < 256) h[t * NB + b] = bbs + sh[t] - hv;
}

// packed pairs: (src&127)<<25 | dst   (dst < 2^25)
__global__ __launch_bounds__(256) void bscatter_k(
    const int* __restrict__ esrc, const int* __restrict__ edst, int E, int chunk,
    const int* __restrict__ h, uint32* __restrict__ pairs, int NB) {
  __shared__ int lcur[1024];
  int t = threadIdx.x;
  for (int i = t; i < NB; i += 256) lcur[i] = h[blockIdx.x * NB + i];
  __syncthreads();
  int e0 = blockIdx.x * chunk;
  int e1 = min(e0 + chunk, E);
  for (int e = e0 + t; e < e1; e += 256) {
    int s = esrc[e], d = edst[e];
    int pos = atomicAdd(&lcur[s >> BSHIFT], 1);
    pairs[pos] = ((uint32)(s & 127) << 25) | (uint32)d;
  }
}

__global__ __launch_bounds__(256) void countN_k(
    const uint32* __restrict__ pairs, const int* __restrict__ base,
    int* __restrict__ cnt, float2* __restrict__ dd, int n) {
  __shared__ int c128[128];
  int b = blockIdx.x, t = threadIdx.x;
  if (t < 128) c128[t] = 0;
  __syncthreads();
  int lo = base[b], hi = base[b + 1];
  for (int i = lo + t; i < hi; i += 256) atomicAdd(&c128[pairs[i] >> 25], 1);
  __syncthreads();
  if (t < 128) {
    int node = b * 128 + t;
    if (node < n) {
      int c = c128[t];
      cnt[node] = c;
      float d = (float)(c + 1);  // +1 self loop
      dd[node] = make_float2(rsqrtf(d), 1.f / d);
    }
  }
}

__global__ __launch_bounds__(256) void partC_k(
    const uint32* __restrict__ pairs, const int* __restrict__ base,
    const int* __restrict__ rs, int* __restrict__ csr, int n) {
  __shared__ int lcur[128];
  int b = blockIdx.x, t = threadIdx.x;
  if (t < 128) {
    int node = b * 128 + t;
    lcur[t] = (node < n) ? rs[node] : 0;
  }
  __syncthreads();
  int lo = base[b], hi = base[b + 1];
  for (int i = lo + t; i < hi; i += 256) {
    uint32 p = pairs[i];
    int pos = atomicAdd(&lcur[p >> 25], 1);
    csr[pos] = (int)(p & 0x1FFFFFFu);
  }
}

// ---------------- padded row-start scan ----------------
__global__ void scan1_k(const int* __restrict__ cnt, int* __restrict__ excl,
                        int* __restrict__ bsum, int n) {
  __shared__ int sh[256];
  int t = threadIdx.x, idx = blockIdx.x * 256 + t;
  int v = (idx < n) ? ((cnt[idx] + 3) & ~3) : 0;
  sh[t] = v;
  __syncthreads();
  for (int off = 1; off < 256; off <<= 1) {
    int add = (t >= off) ? sh[t - off] : 0;
    __syncthreads();
    sh[t] += add;
    __syncthreads();
  }
  if (idx < n) excl[idx] = sh[t] - v;
  if (t == 255) bsum[blockIdx.x] = sh[255];
}

__global__ __launch_bounds__(512) void scan3m_k(int* __restrict__ excl,
                                                const int* __restrict__ bsum,
                                                int nb, int n) {
  __shared__ int sh[512];
  int t = threadIdx.x;
  int v = (t < nb) ? bsum[t] : 0;
  sh[t] = v;
  __syncthreads();
  for (int off = 1; off < 512; off <<= 1) {
    int add = (t >= off) ? sh[t - off] : 0;
    __syncthreads();
    sh[t] += add;
    __syncthreads();
  }
  int idx = blockIdx.x * 512 + t;
  if (idx < n) {
    int k = idx >> 8;
    excl[idx] += (k > 0) ? sh[k - 1] : 0;
  }
}

// ---------------- GEMM1 (gemm1f, proven): Hcat = act(x @ W1t^T + b) ----------
__global__ __launch_bounds__(256) void gemm1f_k(
    const float* __restrict__ A, const _Float16* __restrict__ Bt,
    const float* __restrict__ b0, const float* __restrict__ b1,
    _Float16* __restrict__ out, int M, int mtiles) {
  __shared__ __align__(16) unsigned char ldsb[49152];

  const int sg = blockIdx.x >> 5, loc = blockIdx.x & 31;
  const int nt = loc >> 3, mtl = loc & 7;
  const int mt = sg * 8 + mtl;
  if (mt >= mtiles) return;
  const int m0 = mt * 128, n0 = nt * 128;
  const int t = threadIdx.x;
  const int lane = t & 63;
  const int wave = t >> 6;
  const int wm = wave >> 1, wn = wave & 1;
  const int lr = lane & 15, quad = lane >> 4;

  const int ra = t >> 3;
  const int asw = ((t & 7) ^ (ra & 7)) << 2;
  const int rb = t >> 2;
  const int bsw = ((t & 3) ^ ((t >> 3) & 3)) << 3;

  f32x4 acc[4][4] = {};

  auto stage = [&](int b, int kt) {
#pragma unroll
    for (int i = 0; i < 4; i++) {
      const float* src = A + (size_t)min(m0 + i * 32 + ra, M - 1) * 512 + kt + asw;
      gload16(src, ldsb + b * 16384 + i * 4096 + t * 16);
    }
#pragma unroll
    for (int i = 0; i < 2; i++) {
      const _Float16* src = Bt + (size_t)(n0 + i * 64 + rb) * 512 + kt + bsw;
      gload16(src, ldsb + 32768 + b * 8192 + i * 4096 + t * 16);
    }
  };

  stage(0, 0);
  __syncthreads();

  int cur = 0;
  const int zA = lr & 7;
  const int zB = (lr >> 1) & 3;
  for (int kt = 0; kt < 512; kt += 32) {
    if (kt + 32 < 512) stage(cur ^ 1, kt + 32);
    const unsigned char* Ab = ldsb + cur * 16384;
    const unsigned char* Bb = ldsb + 32768 + cur * 8192;
    h8 bf[4];
#pragma unroll
    for (int j = 0; j < 4; j++) {
      int row = wn * 64 + j * 16 + lr;
      bf[j] = *(const h8*)(Bb + row * 64 + ((quad ^ zB) << 4));
    }
    h8 af[4];
#pragma unroll
    for (int i = 0; i < 4; i++) {
      int R = wm * 64 + i * 16 + lr;
      const float4 a0 = *(const float4*)(Ab + R * 128 + (((2 * quad) ^ zA) << 4));
      const float4 a1 = *(const float4*)(Ab + R * 128 + (((2 * quad + 1) ^ zA) << 4));
      af[i] = cvt8(a0, a1);
    }
#pragma unroll
    for (int i = 0; i < 4; i++)
#pragma unroll
      for (int j = 0; j < 4; j++)
        acc[i][j] = __builtin_amdgcn_mfma_f32_16x16x32_f16(af[i], bf[j], acc[i][j], 0, 0, 0);
    __syncthreads();
    cur ^= 1;
  }

  // epilogue: bias+act in regs -> f16 LDS tile (stride 136) -> 16B coalesced stores
  _Float16* lt = (_Float16*)ldsb;
#pragma unroll
  for (int j = 0; j < 4; j++) {
    int gc = n0 + wn * 64 + j * 16 + lr;
    float bj = (gc < 256) ? b0[gc] : b1[gc - 256];
#pragma unroll
    for (int i = 0; i < 4; i++) {
#pragma unroll
      for (int r = 0; r < 4; r++) {
        float z = acc[i][j][r] + bj;
        float v = (gc < 256) ? elu_f(z) : fmaxf(z, 0.f);
        lt[(wm * 64 + i * 16 + quad * 4 + r) * 136 + wn * 64 + j * 16 + lr] = (_Float16)v;
      }
    }
  }
  __syncthreads();
  {
    const int row = t >> 1, col0 = (t & 1) * 64;
    const int gr = m0 + row;
    if (gr < M) {
      _Float16* dst = out + (size_t)gr * 512 + n0 + col0;
#pragma unroll
      for (int k = 0; k < 8; k++)
        *(h8*)(dst + k * 8) = *(h8*)&lt[row * 136 + col0 + k * 8];
    }
  }
}

// ---------------- GEMM2 + fused attention (gload16-staged) ----------------
__global__ __launch_bounds__(256) void gemm2_k(
    const _Float16* __restrict__ A, const _Float16* __restrict__ Bt,
    const float* __restrict__ bm1, const float* __restrict__ bv1,
    const float2* __restrict__ dd, uint32* __restrict__ Mcat, int M) {
  __shared__ __align__(16) unsigned char ldsb[32768];
  const int m0 = blockIdx.x * 128;
  const int t = threadIdx.x;
  const int lane = t & 63;
  const int wave = t >> 6;
  const int lr = lane & 15, quad = lane >> 4;

  const int rb = t >> 2;
  const int sw = ((t & 3) ^ ((t >> 3) & 3)) << 3;     // inv-swizzled f16 col

  f32x4 acc[2][8] = {};

  auto stage = [&](int b, int kt) {
#pragma unroll
    for (int i = 0; i < 2; i++) {                     // A: 128 rows x 32 f16
      const _Float16* src = A + (size_t)min(m0 + i * 64 + rb, M - 1) * 512 + kt + sw;
      gload16(src, ldsb + b * 16384 + i * 4096 + t * 16);
    }
#pragma unroll
    for (int i = 0; i < 2; i++) {                     // B: 128 rows x 32 f16
      const _Float16* src = Bt + (size_t)(i * 64 + rb) * 512 + kt + sw;
      gload16(src, ldsb + b * 16384 + 8192 + i * 4096 + t * 16);
    }
  };

  stage(0, 0);
  __syncthreads();

  const int z = (lr >> 1) & 3;
  int cur = 0;
  for (int kt = 0; kt < 512; kt += 32) {
    if (kt + 32 < 512) stage(cur ^ 1, kt + 32);
    const unsigned char* Ab = ldsb + cur * 16384;
    const unsigned char* Bb = Ab + 8192;
    h8 af[2], bf[8];
#pragma unroll
    for (int i = 0; i < 2; i++) {
      int row = wave * 32 + i * 16 + lr;
      af[i] = *(const h8*)(Ab + row * 64 + ((quad ^ z) << 4));
    }
#pragma unroll
    for (int j = 0; j < 8; j++) {
      int row = j * 16 + lr;
      bf[j] = *(const h8*)(Bb + row * 64 + ((quad ^ z) << 4));
    }
#pragma unroll
    for (int i = 0; i < 2; i++)
#pragma unroll
      for (int j = 0; j < 8; j++)
        acc[i][j] = __builtin_amdgcn_mfma_f32_16x16x32_f16(af[i], bf[j], acc[i][j], 0, 0, 0);
    __syncthreads();
    cur ^= 1;
  }

  float2 wrow[2][4];
#pragma unroll
  for (int i = 0; i < 2; i++)
#pragma unroll
    for (int r = 0; r < 4; r++) {
      int gr = m0 + wave * 32 + i * 16 + quad * 4 + r;
      wrow[i][r] = (gr < M) ? dd[gr] : make_float2(0.f, 0.f);
    }

#pragma unroll
  for (int jm = 0; jm < 4; jm++) {
    int c = jm * 16 + lr;                 // class col 0..63
    float bm = bm1[c], bv = bv1[c];
#pragma unroll
    for (int i = 0; i < 2; i++) {
#pragma unroll
      for (int r = 0; r < 4; r++) {
        int gr = m0 + wave * 32 + i * 16 + quad * 4 + r;
        if (gr < M) {
          float zm = acc[i][jm][r] + bm;
          float zv = acc[i][4 + jm][r] + bv;
          float m = elu_f(zm);
          float v = fmaxf(zv, 0.f) + 1e-6f;
          float a = __expf(-v);
          h2 pk;
          pk.x = (_Float16)(m * a * wrow[i][r].x);       // dis_r * mean*attn
          pk.y = (_Float16)(v * a * a * wrow[i][r].y);   // di_r * var*attn^2
          Mcat[(size_t)gr * 64 + c] = __builtin_bit_cast(uint32, pk);
        }
      }
    }
  }
}

// ---------------- fused dual SpMM + reparam + log_softmax (dual-row) --------
// lanes 0-31 -> row 2i, lanes 32-63 -> row 2i+1; lane handles 2 classes via
// uint2 loads (8B). Same gathered bytes/row (256B), half the VMEM instrs,
// 2 rows/wave. Softmax reduce via width-32 sub-group shuffles.
__global__ __launch_bounds__(256) void spmm_final_k(
    const uint32* __restrict__ Mcat, const float2* __restrict__ dd,
    const int* __restrict__ row_start, const int* __restrict__ cnt,
    const int* __restrict__ csr, const float* __restrict__ sample,
    float* __restrict__ out, int n) {
  int wid = threadIdx.x >> 6, lane = threadIdx.x & 63;
  int half = lane >> 5, sl = lane & 31;
  int r = blockIdx.x * 8 + wid * 2 + half;
  if (r >= n) return;
  float2 wr = dd[r];
  uint2 sf = ((const uint2*)(Mcat + (size_t)r * 64))[sl];
  h2 s0 = __builtin_bit_cast(h2, sf.x);
  h2 s1 = __builtin_bit_cast(h2, sf.y);
  float Sm0 = (float)s0.x, Sv0 = (float)s0.y;   // class 2*sl   (pre-scaled)
  float Sm1 = (float)s1.x, Sv1 = (float)s1.y;   // class 2*sl+1
  int start = row_start[r];
  int c = cnt[r];
  int j = 0;
  for (; j + 8 <= c; j += 8) {
    int4 da = *(const int4*)(csr + start + j);
    int4 db = *(const int4*)(csr + start + j + 4);
    uint2 p0 = ((const uint2*)(Mcat + (size_t)da.x * 64))[sl];
    uint2 p1 = ((const uint2*)(Mcat + (size_t)da.y * 64))[sl];
    uint2 p2 = ((const uint2*)(Mcat + (size_t)da.z * 64))[sl];
    uint2 p3 = ((const uint2*)(Mcat + (size_t)da.w * 64))[sl];
    uint2 p4 = ((const uint2*)(Mcat + (size_t)db.x * 64))[sl];
    uint2 p5 = ((const uint2*)(Mcat + (size_t)db.y * 64))[sl];
    uint2 p6 = ((const uint2*)(Mcat + (size_t)db.z * 64))[sl];
    uint2 p7 = ((const uint2*)(Mcat + (size_t)db.w * 64))[sl];
#define ACC2(p)                                                   \
    { h2 a_ = __builtin_bit_cast(h2, p.x);                        \
      h2 b_ = __builtin_bit_cast(h2, p.y);                        \
      Sm0 += (float)a_.x; Sv0 += (float)a_.y;                     \
      Sm1 += (float)b_.x; Sv1 += (float)b_.y; }
    ACC2(p0) ACC2(p1) ACC2(p2) ACC2(p3)
    ACC2(p4) ACC2(p5) ACC2(p6) ACC2(p7)
  }
  if (j + 4 <= c) {
    int4 d4 = *(const int4*)(csr + start + j);
    uint2 p0 = ((const uint2*)(Mcat + (size_t)d4.x * 64))[sl];
    uint2 p1 = ((const uint2*)(Mcat + (size_t)d4.y * 64))[sl];
    uint2 p2 = ((const uint2*)(Mcat + (size_t)d4.z * 64))[sl];
    uint2 p3 = ((const uint2*)(Mcat + (size_t)d4.w * 64))[sl];
    ACC2(p0) ACC2(p1) ACC2(p2) ACC2(p3)
    j += 4;
  }
  for (; j < c; j++) {
    int d = csr[start + j];
    uint2 p = ((const uint2*)(Mcat + (size_t)d * 64))[sl];
    ACC2(p)
  }
#undef ACC2
  float2 sp = ((const float2*)(sample + (size_t)r * 64))[sl];
  float o0 = wr.x * Sm0 + sp.x * sqrtf(wr.y * Sv0);
  float o1 = wr.x * Sm1 + sp.y * sqrtf(wr.y * Sv1);
  float mx = fmaxf(o0, o1);
#pragma unroll
  for (int off = 16; off; off >>= 1) mx = fmaxf(mx, __shfl_xor(mx, off, 32));
  float s = __expf(o0 - mx) + __expf(o1 - mx);
#pragma unroll
  for (int off = 16; off; off >>= 1) s += __shfl_xor(s, off, 32);
  float ls = logf(s);
  ((float2*)(out + (size_t)r * 64))[sl] = make_float2(o0 - mx - ls, o1 - mx - ls);
}

// ---------------- launch ----------------
extern "C" void kernel_launch(void* const* d_in, const int* in_sizes, int n_in,
                              void* d_out, int out_size, void* d_ws, size_t ws_size,
                              hipStream_t stream) {
  (void)n_in; (void)out_size; (void)ws_size;
  const float* x    = (const float*)d_in[0];
  const float* Wm0  = (const float*)d_in[1];
  const float* bm0  = (const float*)d_in[2];
  const float* Wv0  = (const float*)d_in[3];
  const float* bv0  = (const float*)d_in[4];
  const float* Wm1  = (const float*)d_in[5];
  const float* bm1  = (const float*)d_in[6];
  const float* Wv1  = (const float*)d_in[7];
  const float* bv1  = (const float*)d_in[8];
  const float* sample = (const float*)d_in[9];
  const int* esrc   = (const int*)d_in[10];
  const int* edst   = (const int*)d_in[11];
  float* out = (float*)d_out;

  const int N = in_sizes[0] / 512;
  const int E = in_sizes[10];
  const int NB = (N + 127) >> BSHIFT;          // 128-node buckets
  const int chunk = (E + NCHUNK - 1) / NCHUNK;

  uint8_t* p = (uint8_t*)d_ws;
  size_t off = 0;
  auto alloc = [&](size_t bytes) -> void* {
    void* r = p + off;
    off += (bytes + 255) & ~(size_t)255;
    return r;
  };
  _Float16* W1t  = (_Float16*)alloc((size_t)512 * 512 * 2);
  _Float16* W2t  = (_Float16*)alloc((size_t)128 * 512 * 2);
  _Float16* Hcat = (_Float16*)alloc((size_t)N * 512 * 2);
  uint32*   Mcat = (uint32*)alloc((size_t)N * 64 * 4);
  int*   cnt    = (int*)alloc((size_t)N * 4);
  float2* dd    = (float2*)alloc((size_t)N * 8);
  int*   rs     = (int*)alloc((size_t)N * 4);
  int*   h      = (int*)alloc((size_t)NCHUNK * NB * 4);
  int*   tot    = (int*)alloc((size_t)(NB + 1) * 4);
  int*   base   = (int*)alloc((size_t)(NB + 1) * 4);
  int*   bsum   = (int*)alloc(2048);
  int*   csr    = (int*)alloc((size_t)(E + 4 * N) * 4);  // padded rows
  // bucket-sorted packed pairs only live before gemm1 writes Hcat:
  uint32* pairs = (uint32*)Hcat;   // E*4 = 12.8MB <= Hcat's 102.4MB

  const int nbN = (N + 255) / 256;

  histprep_k<<<NCHUNK + 1024, 256, 0, stream>>>(esrc, E, chunk, h, NB,
                                                Wm0, Wv0, Wm1, Wv1, W1t, W2t);
  btotal_k<<<NB, 256, 0, stream>>>(h, tot, NB);
  boff2_k<<<NB, 1024, 0, stream>>>(tot, h, base, NB);
  bscatter_k<<<NCHUNK, 256, 0, stream>>>(esrc, edst, E, chunk, h, pairs, NB);
  countN_k<<<NB, 256, 0, stream>>>(pairs, base, cnt, dd, N);
  scan1_k<<<nbN, 256, 0, stream>>>(cnt, rs, bsum, N);
  scan3m_k<<<(N + 511) / 512, 512, 0, stream>>>(rs, bsum, nbN, N);
  partC_k<<<NB, 256, 0, stream>>>(pairs, base, rs, csr, N);

  const int mtiles = (N + 127) / 128;
  const int sgroups = (mtiles + 7) / 8;
  gemm1f_k<<<sgroups * 32, 256, 0, stream>>>(x, W1t, bm0, bv0, Hcat, N, mtiles);
  gemm2_k<<<mtiles, 256, 0, stream>>>(Hcat, W2t, bm1, bv1, dd, Mcat, N);
  spmm_final_k<<<(N + 7) / 8, 256, 0, stream>>>(Mcat, dd, rs, cnt, csr, sample, out, N);
}